// Round 1
// baseline (908.879 us; speedup 1.0000x reference)
//
#include <hip/hip_runtime.h>
#include <math.h>

// Problem constants (from reference)
#define EMBED 128
#define NPOS  10
#define NNEG  50

// Stable log-sigmoid: log(1/(1+e^-x)) = min(x,0) - log1p(exp(-|x|))
__device__ __forceinline__ float logsigmoid(float x) {
    return fminf(x, 0.0f) - log1pf(__expf(-fabsf(x)));
}

// Full 64-lane butterfly reduction (wave = 64 on CDNA!)
__device__ __forceinline__ float waveReduceSum(float x) {
    #pragma unroll
    for (int off = 32; off > 0; off >>= 1)
        x += __shfl_xor(x, off, 64);
    return x;
}

// One wave per batch element. Lane l owns v[2l:2l+2] as float2.
// Each sample row is gathered as 64 lanes x float2 = one 512B row per
// vector-load instruction (fully coalesced, 8x64B lines, no waste).
__global__ __launch_bounds__(256) void nsloss_kernel(
    const int*   __restrict__ input_labels,   // (B,1)
    const int*   __restrict__ pos_labels,     // (B,NPOS)
    const int*   __restrict__ neg_labels,     // (B,NNEG)
    const float* __restrict__ in_embed,       // (V,EMBED)
    const float* __restrict__ out_embed,      // (V,EMBED)
    float*       __restrict__ out,            // (B,)
    int batch)
{
    const int wave = (int)((blockIdx.x * blockDim.x + threadIdx.x) >> 6);
    const int lane = (int)(threadIdx.x & 63);
    if (wave >= batch) return;
    const int b = wave;

    // Gather the input embedding row (uniform address per wave for the label)
    const long vrow = (long)input_labels[b] * EMBED;
    const float2 v = *reinterpret_cast<const float2*>(in_embed + vrow + 2 * lane);

    float loss = 0.0f;

    // Positive samples: loss += logsig(dot)
    const int* __restrict__ pl = pos_labels + (long)b * NPOS;
    #pragma unroll
    for (int s = 0; s < NPOS; ++s) {
        const long rrow = (long)pl[s] * EMBED;
        const float2 r = *reinterpret_cast<const float2*>(out_embed + rrow + 2 * lane);
        float p = v.x * r.x + v.y * r.y;
        const float dot = waveReduceSum(p);
        loss += logsigmoid(dot);
    }

    // Negative samples: neg_dot = -dot, loss += logsig(-dot)
    const int* __restrict__ nl = neg_labels + (long)b * NNEG;
    #pragma unroll 10
    for (int s = 0; s < NNEG; ++s) {
        const long rrow = (long)nl[s] * EMBED;
        const float2 r = *reinterpret_cast<const float2*>(out_embed + rrow + 2 * lane);
        float p = v.x * r.x + v.y * r.y;
        const float dot = waveReduceSum(p);
        loss += logsigmoid(-dot);
    }

    if (lane == 0) out[b] = -loss;
}

extern "C" void kernel_launch(void* const* d_in, const int* in_sizes, int n_in,
                              void* d_out, int out_size, void* d_ws, size_t ws_size,
                              hipStream_t stream) {
    // setup_inputs() dict order:
    //   0: input_labels (B,1)  int32
    //   1: pos_labels   (B,10) int32
    //   2: neg_labels   (B,50) int32
    //   3: in_embed     (V,128) float32
    //   4: out_embed    (V,128) float32
    const int*   input_labels = (const int*)d_in[0];
    const int*   pos_labels   = (const int*)d_in[1];
    const int*   neg_labels   = (const int*)d_in[2];
    const float* in_embed     = (const float*)d_in[3];
    const float* out_embed    = (const float*)d_in[4];
    float*       out          = (float*)d_out;

    const int batch = in_sizes[0];           // 16384 (input_labels is B*1)
    const int wavesPerBlock = 4;             // 256 threads
    const int blocks = (batch + wavesPerBlock - 1) / wavesPerBlock;

    nsloss_kernel<<<blocks, wavesPerBlock * 64, 0, stream>>>(
        input_labels, pos_labels, neg_labels, in_embed, out_embed, out, batch);
}

// Round 2
// 830.700 us; speedup vs baseline: 1.0941x; 1.0941x over previous
//
#include <hip/hip_runtime.h>
#include <math.h>

#define EMBED 128
#define NPOS  10
#define NNEG  50
#define NTOT  (NPOS + NNEG)   // 60
#define NPASS (NTOT / 4)      // 15 passes, 4 samples (16-lane groups) per pass

// Stable log-sigmoid: log(1/(1+e^-x)) = min(x,0) - log1p(exp(-|x|))
__device__ __forceinline__ float logsigmoid(float x) {
    return fminf(x, 0.0f) - log1pf(__expf(-fabsf(x)));
}

// One wave (64 lanes) per batch element.
// Lane layout: g = lane>>4 selects one of 4 concurrent samples,
//              e = lane&15 selects an 8-float slice of the 128-dim row.
// Per pass: 4 rows gathered via 2 fully-coalesced dwordx4 wave-loads,
// dot = 8 lane-FMAs + 4-step 16-lane butterfly (vs 6-step 64-lane before).
__global__ __launch_bounds__(256) void nsloss_kernel(
    const int*   __restrict__ input_labels,   // (B,1)
    const int*   __restrict__ pos_labels,     // (B,NPOS)
    const int*   __restrict__ neg_labels,     // (B,NNEG)
    const float* __restrict__ in_embed,       // (V,EMBED)
    const float* __restrict__ out_embed,      // (V,EMBED)
    float*       __restrict__ out,            // (B,)
    int batch)
{
    const int wid  = (int)((blockIdx.x * blockDim.x + threadIdx.x) >> 6);
    const int lane = (int)(threadIdx.x & 63);
    if (wid >= batch) return;
    const int b = wid;
    const int g = lane >> 4;     // sample group 0..3
    const int e = lane & 15;     // slice index: floats [8e, 8e+8)

    // Input embedding slice (identical across the 4 groups; broadcast from L1)
    const long vrow = (long)input_labels[b] * EMBED;
    const float4 v0 = *reinterpret_cast<const float4*>(in_embed + vrow + 8 * e);
    const float4 v1 = *reinterpret_cast<const float4*>(in_embed + vrow + 8 * e + 4);

    // Preload all 60 labels for this batch element: lane s holds label of sample s.
    int myLabel = 0;
    if (lane < NPOS)      myLabel = pos_labels[(long)b * NPOS + lane];
    else if (lane < NTOT) myLabel = neg_labels[(long)b * NNEG + (lane - NPOS)];

    float loss = 0.0f;

    #pragma unroll 5
    for (int p = 0; p < NPASS; ++p) {
        const int s   = 4 * p + g;                 // this group's sample index
        const int lbl = __shfl(myLabel, s, 64);    // broadcast label (1 bpermute)

        const float* __restrict__ r = out_embed + (long)lbl * EMBED + 8 * e;
        const float4 r0 = *reinterpret_cast<const float4*>(r);
        const float4 r1 = *reinterpret_cast<const float4*>(r + 4);

        float d = v0.x * r0.x + v0.y * r0.y + v0.z * r0.z + v0.w * r0.w
                + v1.x * r1.x + v1.y * r1.y + v1.z * r1.z + v1.w * r1.w;

        // 16-lane butterfly (xor<16 stays within the group)
        d += __shfl_xor(d, 1, 64);
        d += __shfl_xor(d, 2, 64);
        d += __shfl_xor(d, 4, 64);
        d += __shfl_xor(d, 8, 64);

        // positives use +dot, negatives use -dot (ref: logsig(-neg_dot))
        loss += logsigmoid((s < NPOS) ? d : -d);
    }

    // Sum the 4 group losses (each lane in a group holds identical value)
    loss += __shfl_xor(loss, 16, 64);
    loss += __shfl_xor(loss, 32, 64);

    if (lane == 0) out[b] = -loss;
}

extern "C" void kernel_launch(void* const* d_in, const int* in_sizes, int n_in,
                              void* d_out, int out_size, void* d_ws, size_t ws_size,
                              hipStream_t stream) {
    const int*   input_labels = (const int*)d_in[0];
    const int*   pos_labels   = (const int*)d_in[1];
    const int*   neg_labels   = (const int*)d_in[2];
    const float* in_embed     = (const float*)d_in[3];
    const float* out_embed    = (const float*)d_in[4];
    float*       out          = (float*)d_out;

    const int batch = in_sizes[0];
    const int wavesPerBlock = 4;              // 256 threads
    const int blocks = (batch + wavesPerBlock - 1) / wavesPerBlock;

    nsloss_kernel<<<blocks, wavesPerBlock * 64, 0, stream>>>(
        input_labels, pos_labels, neg_labels, in_embed, out_embed, out, batch);
}